// Round 5
// baseline (369.583 us; speedup 1.0000x reference)
//
#include <hip/hip_runtime.h>

#define N_NODES 100000
#define N_EDGES 1600000
#define IN_CH   64
#define HID_CH  64
#define OUT_CH  128
#define TILE    128
#define DPB     64                              // dsts per edge-block
#define N_EBLK  ((N_NODES + DPB - 1) / DPB)     // 1563
#define N_SCANB ((N_NODES + 255) / 256)         // 391

typedef __attribute__((ext_vector_type(8))) __bf16    bf16x8;
typedef __attribute__((ext_vector_type(4))) float     f32x4;
typedef __attribute__((ext_vector_type(2))) _Float16  f16x2;
typedef __attribute__((ext_vector_type(8))) _Float16  f16x8;

// ---- workspace byte offsets (total ~52.9 MB) ----
#define OFF_HSUM   0            // 100000*64*2  = 12,800,000  (f16, natural ch order)
#define OFF_XB     12800000     // 100000*64*2  = 12,800,000  (bf16 bits)
#define OFF_SREC   25600000     // 1600000*16   = 25,600,000  (sorted edge records)
#define OFF_CNT    51200000     // 100000*4     (float deg)
#define OFF_DEG    51600000     // 100000*4     (u32 masked degree)
#define OFF_RPTR   52000000     // 100001*4     (row_ptr)
#define OFF_CUR    52400016     // 100000*4     (scatter cursors)
#define OFF_BSUM   52800016     // 391*4        (scan block sums)
#define OFF_NTYPE  52801600     // 100000*1

__device__ __forceinline__ unsigned short f2bf(float f) {
    union { float f; unsigned int i; } c;
    c.f = f;
    unsigned int u = c.i;
    unsigned int r = (u + 0x7FFFu + ((u >> 16) & 1u)) >> 16;   // RNE
    return (unsigned short)r;
}

__device__ __forceinline__ bool edge_mask(int ntc, float a0) {
    return (ntc == 0) ? (a0 < 0.5f) : ((ntc == 1) ? (a0 < 0.3f) : true);
}

// prep: x fp32->bf16 + node-type byte table + zero deg
__global__ void gnn_prep(const float* __restrict__ xf,
                         unsigned short* __restrict__ xb,
                         unsigned char* __restrict__ ntype,
                         uint4* __restrict__ degz) {   // deg as uint4 (25k)
    int i = blockIdx.x * blockDim.x + threadIdx.x;
    if (i < 1600000) {
        float4 v = reinterpret_cast<const float4*>(xf)[i];
        ushort4 o;
        o.x = f2bf(v.x); o.y = f2bf(v.y); o.z = f2bf(v.z); o.w = f2bf(v.w);
        reinterpret_cast<ushort4*>(xb)[i] = o;
        if ((i & 15) == 0) {
            int n = i >> 4;
            ntype[n] = (v.x == 0.0f) ? 0 : ((v.x == 1.0f) ? 1 : 2);
        }
    } else if (i < 1625000) {
        degz[i - 1600000] = (uint4){0u, 0u, 0u, 0u};
    }
}

// hist: masked in-degree per dst
__global__ void gnn_hist(const int* __restrict__ eidx,
                         const float* __restrict__ ea,
                         const unsigned char* __restrict__ ntype,
                         unsigned int* __restrict__ deg) {
    int e = blockIdx.x * blockDim.x + threadIdx.x;
    if (e < N_EDGES) {
        int s = eidx[e];
        float a0 = ea[e * 3];
        if (edge_mask(ntype[s], a0))
            atomicAdd(deg + eidx[N_EDGES + e], 1u);
    }
}

// scan pass A: per-256-block exclusive scan of deg -> rptr (local), block sums,
// and cnt = (float)deg for the node kernel.
__global__ void gnn_scan_a(const unsigned int* __restrict__ deg,
                           unsigned int* __restrict__ rptr,
                           unsigned int* __restrict__ bsum,
                           float* __restrict__ cnt) {
    __shared__ unsigned int sd[256];
    int t = threadIdx.x;
    int i = blockIdx.x * 256 + t;
    unsigned v = (i < N_NODES) ? deg[i] : 0u;
    sd[t] = v;
    __syncthreads();
    for (int off = 1; off < 256; off <<= 1) {
        unsigned x = (t >= off) ? sd[t - off] : 0u;
        __syncthreads();
        sd[t] += x;
        __syncthreads();
    }
    unsigned incl = sd[t];
    if (i < N_NODES) {
        rptr[i] = incl - v;          // local exclusive
        cnt[i]  = (float)v;
    }
    if (t == 255) bsum[blockIdx.x] = incl;
}

// scan pass B: single block scans the 391 block sums (in-place exclusive),
// writes grand total to rptr[N_NODES].
__global__ void gnn_scan_b(unsigned int* __restrict__ bsum,
                           unsigned int* __restrict__ rptr) {
    __shared__ unsigned int sd[512];
    int t = threadIdx.x;
    unsigned v = (t < N_SCANB) ? bsum[t] : 0u;
    sd[t] = v;
    __syncthreads();
    for (int off = 1; off < 512; off <<= 1) {
        unsigned x = (t >= off) ? sd[t - off] : 0u;
        __syncthreads();
        sd[t] += x;
        __syncthreads();
    }
    if (t < N_SCANB) bsum[t] = sd[t] - v;   // exclusive
    if (t == 511) rptr[N_NODES] = sd[511];  // total masked-in edges
}

// scan pass C: add block offsets -> absolute rptr; init scatter cursors.
__global__ void gnn_scan_c(unsigned int* __restrict__ rptr,
                           const unsigned int* __restrict__ bsum,
                           unsigned int* __restrict__ cur) {
    int i = blockIdx.x * 256 + threadIdx.x;
    if (i < N_NODES) {
        unsigned r = rptr[i] + bsum[blockIdx.x];
        rptr[i] = r;
        cur[i]  = r;
    }
}

// scatter: counting-sort masked-in edges by dst. Record = {src, dst, a0, a1|a2 f16}.
__global__ void gnn_scatter(const int* __restrict__ eidx,
                            const float* __restrict__ ea,
                            const unsigned char* __restrict__ ntype,
                            unsigned int* __restrict__ cur,
                            float4* __restrict__ srec) {
    int e = blockIdx.x * blockDim.x + threadIdx.x;
    if (e < N_EDGES) {
        int s = eidx[e];
        float a0 = ea[e * 3 + 0];
        if (edge_mask(ntype[s], a0)) {
            int d = eidx[N_EDGES + e];
            float a1 = ea[e * 3 + 1];
            float a2 = ea[e * 3 + 2];
            unsigned pos = atomicAdd(cur + d, 1u);
            union { f16x2 v; float f; } pk;
            pk.v = (f16x2){(_Float16)a1, (_Float16)a2};
            float4 rec;
            rec.x = __int_as_float(s);
            rec.y = __int_as_float(d);
            rec.z = a0;
            rec.w = pk.f;
            srec[pos] = rec;
        }
    }
}

// Sorted edge kernel: block b owns dsts [b*64, b*64+64) exclusively.
// h_e = relu([x_dst|x_src|ea]@W1+b1) accumulated into an LDS fp32 tile via
// run-compressed ds-atomics (edges sorted by dst -> runs of equal dst), then
// flushed to hsum with PLAIN stores. Zero global atomics; masked-out edges
// were dropped at sort time (40% less gather + MFMA than the atomic version).
__global__ __launch_bounds__(256, 4) void gnn_edge_sorted(
    const unsigned short* __restrict__ xb,    // [N_NODES][64] bf16 bits
    const float4*         __restrict__ srec,  // sorted records
    const unsigned int*   __restrict__ rptr,  // [N_NODES+1]
    const float*          __restrict__ W1,    // [131][64]
    const float*          __restrict__ b1,    // [64]
    unsigned int*         __restrict__ hsum)  // [N_NODES][32] f16 pairs (natural)
{
    __shared__ __align__(16) unsigned short W1T[64][136];  // k<128 bf16; 128..135 float4 tail
    __shared__ float accum[65][64];   // [dstLocal][ch]; row 64 = pad trash
    __shared__ float eas[128][3];
    __shared__ int   srcs[128];
    __shared__ int   dstg[128];       // global dst (gather)
    __shared__ int   dstl[128];       // local dst 0..64

    const int tid  = threadIdx.x;
    const int wave = tid >> 6;
    const int lane = tid & 63;
    const int q    = lane >> 4;
    const int m16  = lane & 15;

    // ---- stage W1 (fp32 -> bf16) + tail ----
    for (int idx = tid; idx < 128 * 64; idx += 256) {
        int k = idx >> 6, n = idx & 63;
        W1T[n][k] = f2bf(W1[idx]);
    }
    if (tid < 64) {
        float4 tl;
        tl.x = W1[128 * 64 + tid];
        tl.y = W1[129 * 64 + tid];
        tl.z = W1[130 * 64 + tid];
        tl.w = b1[tid];
        *reinterpret_cast<float4*>(&W1T[tid][128]) = tl;
    }
    // ---- zero accum ----
    for (int idx = tid; idx < 65 * 64; idx += 256)
        (&accum[0][0])[idx] = 0.0f;

    const int base = blockIdx.x * DPB;
    const int dEnd = (base + DPB < N_NODES) ? base + DPB : N_NODES;
    const unsigned eStart = rptr[base];
    const unsigned eEnd   = rptr[dEnd];
    __syncthreads();

    const int ebase = wave * 32;

    for (unsigned t0 = eStart; t0 < eEnd; t0 += TILE) {
        int cntE = (int)(eEnd - t0); if (cntE > TILE) cntE = TILE;
        if (tid < TILE) {
            if (tid < cntE) {
                float4 rec = srec[t0 + tid];
                int s = __float_as_int(rec.x);
                int d = __float_as_int(rec.y);
                srcs[tid] = s; dstg[tid] = d; dstl[tid] = d - base;
                union { float f; f16x2 v; } pk; pk.f = rec.w;
                eas[tid][0] = rec.z;
                eas[tid][1] = (float)pk.v[0];
                eas[tid][2] = (float)pk.v[1];
            } else {
                srcs[tid] = 0; dstg[tid] = 0; dstl[tid] = 64;  // pad -> trash row
                eas[tid][0] = 0.f; eas[tid][1] = 0.f; eas[tid][2] = 0.f;
            }
        }
        __syncthreads();

        // ---- acc init: b1 + ea @ W1[128:131] ----
        f32x4 acc1[2][4];
#pragma unroll
        for (int mt = 0; mt < 2; ++mt) {
            float e0[4], e1[4], e2[4];
#pragma unroll
            for (int r = 0; r < 4; ++r) {
                int el = ebase + mt * 16 + q * 4 + r;
                e0[r] = eas[el][0]; e1[r] = eas[el][1]; e2[r] = eas[el][2];
            }
#pragma unroll
            for (int nt = 0; nt < 4; ++nt) {
                int n = nt * 16 + m16;
                float4 wt = *reinterpret_cast<const float4*>(&W1T[n][128]);
#pragma unroll
                for (int r = 0; r < 4; ++r)
                    acc1[mt][nt][r] = wt.w + e0[r] * wt.x + e1[r] * wt.y + e2[r] * wt.z;
            }
        }

        // ---- K=128 MFMA: [x_dst | x_src] (x_dst ~sequential thanks to sort) ----
#pragma unroll
        for (int kc = 0; kc < 4; ++kc) {
            bf16x8 af[2];
#pragma unroll
            for (int mt = 0; mt < 2; ++mt) {
                int el = ebase + mt * 16 + m16;
                int node = (kc < 2) ? dstg[el] : srcs[el];
                af[mt] = *reinterpret_cast<const bf16x8*>(
                    xb + (size_t)node * IN_CH + (kc & 1) * 32 + q * 8);
            }
#pragma unroll
            for (int nt = 0; nt < 4; ++nt) {
                bf16x8 bfr = *reinterpret_cast<const bf16x8*>(
                    &W1T[nt * 16 + m16][kc * 32 + q * 8]);
                acc1[0][nt] = __builtin_amdgcn_mfma_f32_16x16x32_bf16(af[0], bfr, acc1[0][nt], 0, 0, 0);
                acc1[1][nt] = __builtin_amdgcn_mfma_f32_16x16x32_bf16(af[1], bfr, acc1[1][nt], 0, 0, 0);
            }
        }

        // ---- epilogue: relu -> run-compressed LDS accumulation ----
#pragma unroll
        for (int mt = 0; mt < 2; ++mt) {
            int rowb = ebase + mt * 16 + q * 4;
            int d0 = dstl[rowb + 0];
            int d1 = dstl[rowb + 1];
            int d2 = dstl[rowb + 2];
            int d3 = dstl[rowb + 3];
#pragma unroll
            for (int nt = 0; nt < 4; ++nt) {
                int ch = nt * 16 + m16;
                float v0 = acc1[mt][nt][0]; v0 = v0 > 0.f ? v0 : 0.f;
                float v1 = acc1[mt][nt][1]; v1 = v1 > 0.f ? v1 : 0.f;
                float v2 = acc1[mt][nt][2]; v2 = v2 > 0.f ? v2 : 0.f;
                float v3 = acc1[mt][nt][3]; v3 = v3 > 0.f ? v3 : 0.f;
                float s = v0; int cur = d0;
                if (d1 == cur) s += v1; else { atomicAdd(&accum[cur][ch], s); s = v1; cur = d1; }
                if (d2 == cur) s += v2; else { atomicAdd(&accum[cur][ch], s); s = v2; cur = d2; }
                if (d3 == cur) s += v3; else { atomicAdd(&accum[cur][ch], s); s = v3; cur = d3; }
                atomicAdd(&accum[cur][ch], s);
            }
        }
        __syncthreads();   // accum adds + LDS reads done before next staging
    }

    // ---- flush: accum fp32 -> hsum f16 pairs, plain coalesced stores ----
    for (int idx = tid; idx < DPB * 32; idx += 256) {
        int d = idx >> 5;        // 0..63
        int c = idx & 31;        // dword: channels 2c, 2c+1
        int gd = base + d;
        if (gd < N_NODES) {
            union { f16x2 v; unsigned u; } pk;
            pk.v = (f16x2){(_Float16)accum[d][2 * c], (_Float16)accum[d][2 * c + 1]};
            hsum[(size_t)gd * 32 + c] = pk.u;
        }
    }
}

// Node kernel (MFMA): out[n] = relu(hsum[n] @ W2 + cnt[n]*b2).
// hsum is f16 in NATURAL channel order now (plain-store flush).
__global__ __launch_bounds__(256, 4) void gnn_node_out(
    const _Float16* __restrict__ hsum,  // [N_NODES][64] f16
    const float*    __restrict__ cnt,   // [N_NODES]
    const float*    __restrict__ W2,    // [64][128]
    const float*    __restrict__ b2,    // [128]
    float*          __restrict__ out)   // [N_NODES][128]
{
    __shared__ __align__(16) unsigned short W2T[128][72];  // W2T[n][k]=W2[k][n]
    __shared__ float b2s[128];

    const int tid  = threadIdx.x;
    const int wave = tid >> 6;
    const int lane = tid & 63;
    const int q    = lane >> 4;
    const int m16  = lane & 15;

    const int nodeBase = (blockIdx.x * 4 + wave) * 32;

    // prefetch this wave's hsum rows + cnt before LDS staging (hide HBM latency)
    f16x8 hpre[2][2];
    float cc[2][4];
#pragma unroll
    for (int kc = 0; kc < 2; ++kc)
#pragma unroll
        for (int mt = 0; mt < 2; ++mt) {
            int node = nodeBase + mt * 16 + m16;
            if (node >= N_NODES) node = N_NODES - 1;
            hpre[kc][mt] = *reinterpret_cast<const f16x8*>(
                hsum + (size_t)node * HID_CH + kc * 32 + q * 8);
        }
#pragma unroll
    for (int mt = 0; mt < 2; ++mt)
#pragma unroll
        for (int r = 0; r < 4; ++r) {
            int n = nodeBase + mt * 16 + q * 4 + r;
            cc[mt][r] = (n < N_NODES) ? cnt[n] : 0.0f;
        }

    for (int idx = tid; idx < 64 * 128; idx += 256) {
        int k = idx >> 7, n = idx & 127;
        W2T[n][k] = f2bf(W2[k * 128 + n]);
    }
    if (tid < 128) b2s[tid] = b2[tid];
    __syncthreads();

    if (nodeBase >= N_NODES) return;

    f32x4 acc[2][8];
#pragma unroll
    for (int mt = 0; mt < 2; ++mt)
#pragma unroll
        for (int nt = 0; nt < 8; ++nt)
            acc[mt][nt] = (f32x4){0.0f, 0.0f, 0.0f, 0.0f};

#pragma unroll
    for (int kc = 0; kc < 2; ++kc) {
        bf16x8 af[2];
#pragma unroll
        for (int mt = 0; mt < 2; ++mt) {
            union { bf16x8 v; unsigned short u[8]; } rr;
#pragma unroll
            for (int j = 0; j < 8; ++j) rr.u[j] = f2bf((float)hpre[kc][mt][j]);
            af[mt] = rr.v;
        }
#pragma unroll
        for (int nt = 0; nt < 8; ++nt) {
            bf16x8 bfr = *reinterpret_cast<const bf16x8*>(
                &W2T[nt * 16 + m16][kc * 32 + q * 8]);
            acc[0][nt] = __builtin_amdgcn_mfma_f32_16x16x32_bf16(af[0], bfr, acc[0][nt], 0, 0, 0);
            acc[1][nt] = __builtin_amdgcn_mfma_f32_16x16x32_bf16(af[1], bfr, acc[1][nt], 0, 0, 0);
        }
    }

#pragma unroll
    for (int mt = 0; mt < 2; ++mt) {
        int nn[4];
#pragma unroll
        for (int r = 0; r < 4; ++r)
            nn[r] = nodeBase + mt * 16 + q * 4 + r;
#pragma unroll
        for (int nt = 0; nt < 8; ++nt) {
            int col = nt * 16 + m16;
            float bb = b2s[col];
#pragma unroll
            for (int r = 0; r < 4; ++r) {
                if (nn[r] < N_NODES) {
                    float v = acc[mt][nt][r] + cc[mt][r] * bb;
                    out[(size_t)nn[r] * OUT_CH + col] = v > 0.0f ? v : 0.0f;
                }
            }
        }
    }
}

extern "C" void kernel_launch(void* const* d_in, const int* in_sizes, int n_in,
                              void* d_out, int out_size, void* d_ws, size_t ws_size,
                              hipStream_t stream) {
    const float* x  = (const float*)d_in[0];
    const int*   ei = (const int*)d_in[1];
    const float* ea = (const float*)d_in[2];
    const float* W1 = (const float*)d_in[3];
    const float* b1 = (const float*)d_in[4];
    const float* W2 = (const float*)d_in[5];
    const float* b2 = (const float*)d_in[6];
    float* out = (float*)d_out;

    char* wsb = (char*)d_ws;
    unsigned int*   hsum  = (unsigned int*)  (wsb + OFF_HSUM);
    unsigned short* xb    = (unsigned short*)(wsb + OFF_XB);
    float4*         srec  = (float4*)        (wsb + OFF_SREC);
    float*          cnt   = (float*)         (wsb + OFF_CNT);
    unsigned int*   deg   = (unsigned int*)  (wsb + OFF_DEG);
    unsigned int*   rptr  = (unsigned int*)  (wsb + OFF_RPTR);
    unsigned int*   curp  = (unsigned int*)  (wsb + OFF_CUR);
    unsigned int*   bsum  = (unsigned int*)  (wsb + OFF_BSUM);
    unsigned char*  ntype = (unsigned char*) (wsb + OFF_NTYPE);

    gnn_prep<<<(1625000 + 255) / 256, 256, 0, stream>>>(x, xb, ntype, (uint4*)deg);
    gnn_hist<<<N_EDGES / 256, 256, 0, stream>>>(ei, ea, ntype, deg);
    gnn_scan_a<<<N_SCANB, 256, 0, stream>>>(deg, rptr, bsum, cnt);
    gnn_scan_b<<<1, 512, 0, stream>>>(bsum, rptr);
    gnn_scan_c<<<N_SCANB, 256, 0, stream>>>(rptr, bsum, curp);
    gnn_scatter<<<N_EDGES / 256, 256, 0, stream>>>(ei, ea, ntype, curp, srec);
    gnn_edge_sorted<<<N_EBLK, 256, 0, stream>>>(xb, srec, rptr, W1, b1, hsum);
    gnn_node_out<<<(N_NODES + 127) / 128, 256, 0, stream>>>(
        (const _Float16*)hsum, cnt, W2, b2, out);
}